// Round 4
// baseline (728.443 us; speedup 1.0000x reference)
//
#include <hip/hip_runtime.h>
#include <hip/hip_bf16.h>

// Shapes (fixed): B=2, L=2048 -> TOK=4096 tokens
//   D_MODEL=1024, D_INNER=2048, D_STATE=16, D_CONV=4, DT_RANK=64, D_FF=4096
#define TOKS 4096
#define DM   1024
#define DI   2048
#define DST  16
#define DTR  64
#define DFF  4096
#define PROJ_LD 128   // x_proj output padded 96 -> 128

// scan chunking
#define NC    32
#define CHUNK 64

typedef __bf16 bf16x8 __attribute__((ext_vector_type(8)));
typedef float  f32x4  __attribute__((ext_vector_type(4)));

__device__ __forceinline__ __bf16 f2bf(float f) {
  union { float f; unsigned u; } v; v.f = f;
  unsigned r = v.u + 0x7fffu + ((v.u >> 16) & 1u);
  union { unsigned short s; __bf16 b; } o; o.s = (unsigned short)(r >> 16);
  return o.b;
}
__device__ __forceinline__ float siluf(float x) { return x / (1.f + __expf(-x)); }
__device__ __forceinline__ float softplusf(float x) { return x > 20.f ? x : log1pf(__expf(x)); }

// async global->LDS, 16B per lane; LDS dest is wave-uniform base + lane*16
__device__ __forceinline__ void gl2lds16(const void* g, void* l) {
  __builtin_amdgcn_global_load_lds((const __attribute__((address_space(1))) void*)g,
                                   (__attribute__((address_space(3))) void*)l, 16, 0, 0);
}

// ---------------------------------------------------------------------------
// Fused f32 -> bf16 conversion for the 7 weight tensors (one launch).
// ---------------------------------------------------------------------------
struct CvtArgs {
  const float* src[7];
  __bf16*      dst[7];
  int nblk[8];
};

__global__ __launch_bounds__(256) void cvt_bf16_kernel(CvtArgs a) {
  int blk = blockIdx.x;
  int seg = 0;
#pragma unroll
  for (int s = 1; s < 7; s++) if (blk >= a.nblk[s]) seg = s;
  size_t base = (size_t)(blk - a.nblk[seg]) * 2048 + threadIdx.x * 8;
  const float* src = a.src[seg] + base;
  __bf16*      dst = a.dst[seg] + base;
  float4 v0 = *(const float4*)src;
  float4 v1 = *(const float4*)(src + 4);
  union { __bf16 b[8]; uint4 u; } t;
  t.b[0]=f2bf(v0.x); t.b[1]=f2bf(v0.y); t.b[2]=f2bf(v0.z); t.b[3]=f2bf(v0.w);
  t.b[4]=f2bf(v1.x); t.b[5]=f2bf(v1.y); t.b[6]=f2bf(v1.z); t.b[7]=f2bf(v1.w);
  *(uint4*)dst = t.u;
}

// ---------------------------------------------------------------------------
// RMSNorm: one block per row of 1024 f32, output bf16.
// ---------------------------------------------------------------------------
__global__ __launch_bounds__(256) void rmsnorm_kernel(const float* __restrict__ x,
                                                      const float* __restrict__ w,
                                                      __bf16* __restrict__ out) {
  int row = blockIdx.x;
  const float* xr = x + (size_t)row * DM;
  float4 v = ((const float4*)xr)[threadIdx.x];
  float ss = v.x*v.x + v.y*v.y + v.z*v.z + v.w*v.w;
#pragma unroll
  for (int o = 32; o > 0; o >>= 1) ss += __shfl_xor(ss, o);
  __shared__ float sred[4];
  if ((threadIdx.x & 63) == 0) sred[threadIdx.x >> 6] = ss;
  __syncthreads();
  float tot = sred[0] + sred[1] + sred[2] + sred[3];
  float scale = rsqrtf(tot * (1.f / DM) + 1e-5f);
  float4 wv = ((const float4*)w)[threadIdx.x];
  union { __bf16 b[4]; ushort4 u; } o;
  o.b[0] = f2bf(v.x * scale * wv.x);
  o.b[1] = f2bf(v.y * scale * wv.y);
  o.b[2] = f2bf(v.z * scale * wv.z);
  o.b[3] = f2bf(v.w * scale * wv.w);
  *(ushort4*)&out[(size_t)row * DM + threadIdx.x * 4] = o.u;
}

// ---------------------------------------------------------------------------
// GEMM: C[M,N] = A[M,K] @ B[N,K]^T, BN=128, BK=32, 4 waves.
// global_load_lds width=16 staging with PERMUTED-GRANULE layout:
//   each 16-row x 32-col tile (1KB) is stored so that granule
//   (row, kgran) sits at lane-slot (kgran*16 + row) -> the MFMA fragment
//   read for lane l is exactly tile_base + l*16 B: linear, conflict-free.
// A_F32 (dt GEMM only): VGPR-cvt staging, old contiguous layout both tiles.
// EPI: 1 = bf16 store, 2 = softplus(acc+bias[col]) f32, 3 = acc+aux f32,
//      4 = silu(aux_bf16)*acc bf16, 5 = atomicAdd f32 (split-K via gridDim.z)
// ---------------------------------------------------------------------------
template<int BM, int A_F32, int EPI>
__global__ __launch_bounds__(256) void gemm2(
    const void* __restrict__ Ap, const __bf16* __restrict__ Bp,
    void* __restrict__ Cp, const void* __restrict__ auxp,
    int N, int K, int lda, int ldb, int ldc)
{
  constexpr int FM = BM / 32;          // frag rows per wave
  constexpr int AI = BM / 64;          // A staging instrs per wave
  __shared__ __bf16 sA[BM * 32];
  __shared__ __bf16 sB[128 * 32];
  const int tid  = threadIdx.x;
  const int wave = tid >> 6, lane = tid & 63;
  const int m0 = blockIdx.y * BM, n0 = blockIdx.x * 128;
  const int wr = wave >> 1, wc = wave & 1;
  const int frow = lane & 15, fq = lane >> 4;

  f32x4 acc[FM][4] = {};

  const int kPer = K / (int)gridDim.z;
  const int kBeg = blockIdx.z * kPer, kEnd = kBeg + kPer;

  // staging lane->global mapping (permuted-granule for bf16 path)
  const int lrow = A_F32 ? (lane >> 2) : (lane & 15);
  const int lcol = A_F32 ? ((lane & 3) * 8) : ((lane >> 4) * 8);

  for (int kt = kBeg; kt < kEnd; kt += 32) {
    if (A_F32) {
      int srow = tid >> 1, sh = (tid & 1) * 16;
      const float* src = (const float*)Ap + (size_t)(m0 + srow) * lda + kt + sh;
      union { __bf16 b[16]; uint4 u[2]; } t;
#pragma unroll
      for (int q = 0; q < 4; q++) {
        float4 v = *(const float4*)(src + q * 4);
        t.b[q*4+0]=f2bf(v.x); t.b[q*4+1]=f2bf(v.y); t.b[q*4+2]=f2bf(v.z); t.b[q*4+3]=f2bf(v.w);
      }
      *(uint4*)&sA[srow * 32 + sh]     = t.u[0];
      *(uint4*)&sA[srow * 32 + sh + 8] = t.u[1];
    } else {
#pragma unroll
      for (int q = 0; q < AI; q++) {
        int idx = wave * AI + q;
        const __bf16* g = (const __bf16*)Ap + (size_t)(m0 + idx * 16 + lrow) * lda + kt + lcol;
        gl2lds16(g, &sA[idx * 512]);
      }
    }
#pragma unroll
    for (int q = 0; q < 2; q++) {
      int idx = wave * 2 + q;
      const __bf16* g = Bp + (size_t)(n0 + idx * 16 + lrow) * ldb + kt + lcol;
      gl2lds16(g, &sB[idx * 512]);
    }
    __syncthreads();

    bf16x8 afr[FM], bfr[4];
    if (A_F32) {
#pragma unroll
      for (int i = 0; i < FM; i++)
        afr[i] = *(const bf16x8*)&sA[(wr * (BM/2) + i * 16 + frow) * 32 + fq * 8];
#pragma unroll
      for (int j = 0; j < 4; j++)
        bfr[j] = *(const bf16x8*)&sB[(wc * 64 + j * 16 + frow) * 32 + fq * 8];
    } else {
#pragma unroll
      for (int i = 0; i < FM; i++)
        afr[i] = *(const bf16x8*)&sA[(wr * (BM/32) + i) * 512 + lane * 8];
#pragma unroll
      for (int j = 0; j < 4; j++)
        bfr[j] = *(const bf16x8*)&sB[(wc * 4 + j) * 512 + lane * 8];
    }
#pragma unroll
    for (int i = 0; i < FM; i++)
#pragma unroll
      for (int j = 0; j < 4; j++)
        acc[i][j] = __builtin_amdgcn_mfma_f32_16x16x32_bf16(afr[i], bfr[j], acc[i][j], 0, 0, 0);
    __syncthreads();
  }

  const float*  auxf = (const float*)auxp;
  const __bf16* auxb = (const __bf16*)auxp;
#pragma unroll
  for (int i = 0; i < FM; i++) {
    int gr = m0 + wr * (BM/2) + i * 16 + fq * 4;
#pragma unroll
    for (int j = 0; j < 4; j++) {
      int gc = n0 + wc * 64 + j * 16 + frow;
#pragma unroll
      for (int r = 0; r < 4; r++) {
        float v = acc[i][j][r];
        size_t off = (size_t)(gr + r) * ldc + gc;
        if (EPI == 1) ((__bf16*)Cp)[off] = f2bf(v);
        else if (EPI == 2) ((float*)Cp)[off] = softplusf(v + auxf[gc]);
        else if (EPI == 3) ((float*)Cp)[off] = v + auxf[off];
        else if (EPI == 4) {
          float g = (float)auxb[off];
          ((__bf16*)Cp)[off] = f2bf(siluf(g) * v);
        } else if (EPI == 5) atomicAdd((float*)Cp + off, v);
      }
    }
  }
  (void)N;
}

// ---------------------------------------------------------------------------
// Causal depthwise conv (width 4) + SiLU.
// ---------------------------------------------------------------------------
__global__ __launch_bounds__(256) void conv_silu_kernel(const __bf16* __restrict__ xz,
                                                        const float* __restrict__ cw,
                                                        const float* __restrict__ cb,
                                                        __bf16* __restrict__ uact) {
  int idx = blockIdx.x * 256 + threadIdx.x;
  int d   = idx & (DI - 1);
  int tok = idx >> 11;
  int l   = tok & 2047;
  float4 wv = *(const float4*)(cw + d * 4);
  const __bf16* up = xz + (size_t)tok * (2 * DI) + d;
  float acc = cb[d];
  if (l >= 3) acc += wv.x * (float)up[-3 * (2 * DI)];
  if (l >= 2) acc += wv.y * (float)up[-2 * (2 * DI)];
  if (l >= 1) acc += wv.z * (float)up[-1 * (2 * DI)];
  acc += wv.w * (float)up[0];
  uact[idx] = f2bf(siluf(acc));
}

// ---------------------------------------------------------------------------
// Selective scan, chunked 2-pass linear recurrence (proj stride = PROJ_LD).
// ---------------------------------------------------------------------------
__global__ __launch_bounds__(64) void scan_pass1(const float* __restrict__ dt,
                                                 const __bf16* __restrict__ uact,
                                                 const float* __restrict__ proj,
                                                 const float* __restrict__ A_log,
                                                 float* __restrict__ aprod,
                                                 float* __restrict__ hend) {
  int lane = threadIdx.x;
  int d = blockIdx.x * 64 + lane;
  int c = blockIdx.y, b = blockIdx.z;
  float An[16], h[16], ap[16];
  {
    const float4* a4 = (const float4*)(A_log + (size_t)d * 16);
#pragma unroll
    for (int q = 0; q < 4; q++) {
      float4 v = a4[q];
      An[q*4+0] = -__expf(v.x); An[q*4+1] = -__expf(v.y);
      An[q*4+2] = -__expf(v.z); An[q*4+3] = -__expf(v.w);
    }
  }
#pragma unroll
  for (int n = 0; n < 16; n++) { h[n] = 0.f; ap[n] = 1.f; }

  size_t tok = (size_t)b * 2048 + (size_t)c * CHUNK;
  const float*  dtp = dt   + tok * DI + d;
  const __bf16* up  = uact + tok * DI + d;
  const float*  pp  = proj + tok * PROJ_LD;

  for (int t = 0; t < CHUNK; t++) {
    float dtv = *dtp;
    float uv  = (float)*up;
    const float4* b4 = (const float4*)(pp + 64);
    float Bv[16];
#pragma unroll
    for (int q = 0; q < 4; q++) {
      float4 v = b4[q];
      Bv[q*4+0]=v.x; Bv[q*4+1]=v.y; Bv[q*4+2]=v.z; Bv[q*4+3]=v.w;
    }
    float du = dtv * uv;
#pragma unroll
    for (int n = 0; n < 16; n++) {
      float dA = __expf(dtv * An[n]);
      ap[n] *= dA;
      h[n] = fmaf(dA, h[n], du * Bv[n]);
    }
    dtp += DI; up += DI; pp += PROJ_LD;
  }

  size_t off = ((size_t)(b * NC + c) * DI + d) * 16;
#pragma unroll
  for (int q = 0; q < 4; q++) {
    *(float4*)(hend  + off + q*4) = make_float4(h[q*4+0],  h[q*4+1],  h[q*4+2],  h[q*4+3]);
    *(float4*)(aprod + off + q*4) = make_float4(ap[q*4+0], ap[q*4+1], ap[q*4+2], ap[q*4+3]);
  }
}

__global__ __launch_bounds__(256) void scan_pass2(const float* __restrict__ aprod,
                                                  const float* __restrict__ hend,
                                                  float* __restrict__ hstart) {
  int idx = blockIdx.x * 256 + threadIdx.x;
  int b  = idx >> 13;
  int r4 = idx & 8191;
  float4 H = make_float4(0.f, 0.f, 0.f, 0.f);
  for (int c = 0; c < NC; c++) {
    size_t off = (size_t)(b * NC + c) * (DI * 16 / 4) + r4;
    ((float4*)hstart)[off] = H;
    float4 a = ((const float4*)aprod)[off];
    float4 e = ((const float4*)hend)[off];
    H.x = fmaf(a.x, H.x, e.x);
    H.y = fmaf(a.y, H.y, e.y);
    H.z = fmaf(a.z, H.z, e.z);
    H.w = fmaf(a.w, H.w, e.w);
  }
}

__global__ __launch_bounds__(64) void scan_pass3(const float* __restrict__ dt,
                                                 const __bf16* __restrict__ uact,
                                                 const float* __restrict__ proj,
                                                 const __bf16* __restrict__ xz,
                                                 const float* __restrict__ A_log,
                                                 const float* __restrict__ Dp,
                                                 const float* __restrict__ hstart,
                                                 __bf16* __restrict__ y) {
  int lane = threadIdx.x;
  int d = blockIdx.x * 64 + lane;
  int c = blockIdx.y, b = blockIdx.z;
  float An[16], h[16];
  {
    const float4* a4 = (const float4*)(A_log + (size_t)d * 16);
#pragma unroll
    for (int q = 0; q < 4; q++) {
      float4 v = a4[q];
      An[q*4+0] = -__expf(v.x); An[q*4+1] = -__expf(v.y);
      An[q*4+2] = -__expf(v.z); An[q*4+3] = -__expf(v.w);
    }
  }
  {
    size_t off = ((size_t)(b * NC + c) * DI + d) * 16;
#pragma unroll
    for (int q = 0; q < 4; q++) {
      float4 v = *(const float4*)(hstart + off + q*4);
      h[q*4+0]=v.x; h[q*4+1]=v.y; h[q*4+2]=v.z; h[q*4+3]=v.w;
    }
  }
  float Dd = Dp[d];

  size_t tok = (size_t)b * 2048 + (size_t)c * CHUNK;
  const float*  dtp = dt   + tok * DI + d;
  const __bf16* up  = uact + tok * DI + d;
  const float*  pp  = proj + tok * PROJ_LD;
  const __bf16* zp  = xz   + tok * (2 * DI) + DI + d;
  __bf16*       yp  = y    + tok * DI + d;

  for (int t = 0; t < CHUNK; t++) {
    float dtv = *dtp;
    float uv  = (float)*up;
    float zv  = (float)*zp;
    const float4* b4 = (const float4*)(pp + 64);
    float Bv[16], Cv[16];
#pragma unroll
    for (int q = 0; q < 4; q++) {
      float4 v = b4[q];
      Bv[q*4+0]=v.x; Bv[q*4+1]=v.y; Bv[q*4+2]=v.z; Bv[q*4+3]=v.w;
      float4 w = b4[q + 4];
      Cv[q*4+0]=w.x; Cv[q*4+1]=w.y; Cv[q*4+2]=w.z; Cv[q*4+3]=w.w;
    }
    float du = dtv * uv;
    float p = 0.f;
#pragma unroll
    for (int n = 0; n < 16; n++) {
      float dA = __expf(dtv * An[n]);
      h[n] = fmaf(dA, h[n], du * Bv[n]);
      p = fmaf(h[n], Cv[n], p);
    }
    *yp = f2bf((p + Dd * uv) * siluf(zv));
    dtp += DI; up += DI; pp += PROJ_LD; zp += 2 * DI; yp += DI;
  }
}

// ---------------------------------------------------------------------------
extern "C" void kernel_launch(void* const* d_in, const int* in_sizes, int n_in,
                              void* d_out, int out_size, void* d_ws, size_t ws_size,
                              hipStream_t stream) {
  const float* x        = (const float*)d_in[0];
  const float* n1w      = (const float*)d_in[1];
  const float* n2w      = (const float*)d_in[2];
  const float* in_projw = (const float*)d_in[3];
  const float* conv_w   = (const float*)d_in[4];
  const float* conv_b   = (const float*)d_in[5];
  const float* x_projw  = (const float*)d_in[6];
  const float* dt_projw = (const float*)d_in[7];
  const float* dt_projb = (const float*)d_in[8];
  const float* A_log    = (const float*)d_in[9];
  const float* Dp       = (const float*)d_in[10];
  const float* out_projw= (const float*)d_in[11];
  const float* w1       = (const float*)d_in[12];
  const float* w2       = (const float*)d_in[13];
  const float* w3       = (const float*)d_in[14];
  float* out = (float*)d_out;

  char* ws = (char*)d_ws;
  __bf16* xz   = (__bf16*)(ws + 0);            // 4096x4096 bf16 = 33554432
  __bf16* uact = (__bf16*)(ws + 33554432);     // 4096x2048 bf16 = 16777216
  float*  proj = (float*) (ws + 50331648);     // 4096x128 f32  =  2097152
  float*  dt   = (float*) (ws + 52428800);     // 4096x2048 f32 = 33554432
  __bf16* yb   = (__bf16*)(ws + 85983232);     // 4096x2048 bf16= 16777216
  float*  h    = (float*) (ws + 102760448);    // 4096x1024 f32 = 16777216
  __bf16* xn   = (__bf16*)(ws + 119537664);    // 4096x1024 bf16=  8388608
  __bf16* g1   = xz;                           // union: reused after scan
  __bf16* hid  = (__bf16*)dt;                  // union: reused after scan
  float* aprod  = (float*)(ws + 102760448);    // 8388608 (overlaps h)
  float* hend   = (float*)(ws + 111149056);    // 8388608
  float* hstart = (float*)(ws + 119537664);    // 8388608 (overlaps xn)
  char* wb = ws + 127926272;
  __bf16* b_in  = (__bf16*)(wb);               // 8388608
  __bf16* b_xp  = (__bf16*)(wb + 8388608);     // 128x2048 (padded) = 524288
  __bf16* b_dtp = (__bf16*)(wb + 8912896);     // 262144
  __bf16* b_out = (__bf16*)(wb + 9175040);     // 4194304
  __bf16* b_w1  = (__bf16*)(wb + 13369344);    // 8388608
  __bf16* b_w2  = (__bf16*)(wb + 21757952);    // 8388608
  __bf16* b_w3  = (__bf16*)(wb + 30146560);    // 8388608, end 38535168

  // zero-init: x_proj pad rows + split-K accumulator
  hipMemsetAsync(b_xp, 0, 128 * 2048 * sizeof(__bf16), stream);
  hipMemsetAsync(proj, 0, TOKS * PROJ_LD * sizeof(float), stream);

  CvtArgs ca;
  const float* srcs[7] = {in_projw, x_projw, dt_projw, out_projw, w1, w2, w3};
  __bf16* dsts[7]      = {b_in, b_xp, b_dtp, b_out, b_w1, b_w2, b_w3};
  int counts[7] = {4096*1024, 96*2048, 2048*64, 1024*2048, 4096*1024, 4096*1024, 1024*4096};
  int acc = 0;
  for (int i = 0; i < 7; i++) { ca.src[i] = srcs[i]; ca.dst[i] = dsts[i]; ca.nblk[i] = acc; acc += counts[i] / 2048; }
  ca.nblk[7] = acc;
  cvt_bf16_kernel<<<acc, 256, 0, stream>>>(ca);

  dim3 blk(256);
  // 1. xn = rmsnorm(x, norm1_w)
  rmsnorm_kernel<<<TOKS, 256, 0, stream>>>(x, n1w, xn);
  // 2. xz = xn @ in_proj_w.T          (4096x4096, K=1024) -> bf16
  gemm2<128,0,1><<<dim3(32,32,1), blk, 0, stream>>>(xn, b_in, xz, nullptr, 2*DI, DM, DM, DM, 2*DI);
  // 3. u_act = silu(causal_conv(u))   -> bf16
  conv_silu_kernel<<<(TOKS*DI)/256, 256, 0, stream>>>(xz, conv_w, conv_b, uact);
  // 4. proj += u_act @ x_proj_w.T     (4096x128pad, K=2048, split-K x8, atomic)
  gemm2<128,0,5><<<dim3(1,32,8), blk, 0, stream>>>(uact, b_xp, proj, nullptr, PROJ_LD, DI, DI, DI, PROJ_LD);
  // 5. dt = softplus(dt_r @ dt_proj_w.T + b)   (4096x2048, K=64) -> f32
  gemm2<128,1,2><<<dim3(16,32,1), blk, 0, stream>>>(proj, b_dtp, dt, dt_projb, DI, DTR, PROJ_LD, DTR, DI);
  // 6. selective scan (chunked 2-pass) -> y (bf16)
  scan_pass1<<<dim3(DI/64, NC, 2), 64, 0, stream>>>(dt, uact, proj, A_log, aprod, hend);
  scan_pass2<<<64, 256, 0, stream>>>(aprod, hend, hstart);
  scan_pass3<<<dim3(DI/64, NC, 2), 64, 0, stream>>>(dt, uact, proj, xz, A_log, Dp, hstart, yb);
  // 7. h = y @ out_proj_w.T + x       (4096x1024, K=2048) -> f32, BM=64
  gemm2<64,0,3><<<dim3(8,64,1), blk, 0, stream>>>(yb, b_out, h, x, DM, DI, DI, DI, DM);
  // 8. xn = rmsnorm(h, norm2_w)
  rmsnorm_kernel<<<TOKS, 256, 0, stream>>>(h, n2w, xn);
  // 9. g1 = xn @ w1.T                 (4096x4096, K=1024) -> bf16 (reuses xz)
  gemm2<128,0,1><<<dim3(32,32,1), blk, 0, stream>>>(xn, b_w1, g1, nullptr, DFF, DM, DM, DM, DFF);
  // 10. hid = silu(g1) * (xn @ w2.T)  -> bf16 (reuses dt)
  gemm2<128,0,4><<<dim3(32,32,1), blk, 0, stream>>>(xn, b_w2, hid, g1, DFF, DM, DM, DM, DFF);
  // 11. out = hid @ w3.T + h          (4096x1024, K=4096) -> f32, BM=64
  gemm2<64,0,3><<<dim3(8,64,1), blk, 0, stream>>>(hid, b_w3, out, h, DM, DFF, DFF, DFF, DM);

  (void)in_sizes; (void)n_in; (void)out_size; (void)ws_size;
}

// Round 5
// 670.574 us; speedup vs baseline: 1.0863x; 1.0863x over previous
//
#include <hip/hip_runtime.h>
#include <hip/hip_bf16.h>

// Shapes (fixed): B=2, L=2048 -> TOK=4096 tokens
#define TOKS 4096
#define DM   1024
#define DI   2048
#define DST  16
#define DTR  64
#define DFF  4096
#define PROJ_LD 128   // x_proj output padded 96 -> 128

// scan chunking
#define NC    32
#define CHUNK 64

typedef __bf16 bf16x8 __attribute__((ext_vector_type(8)));
typedef float  f32x4  __attribute__((ext_vector_type(4)));

__device__ __forceinline__ __bf16 f2bf(float f) {
  union { float f; unsigned u; } v; v.f = f;
  unsigned r = v.u + 0x7fffu + ((v.u >> 16) & 1u);
  union { unsigned short s; __bf16 b; } o; o.s = (unsigned short)(r >> 16);
  return o.b;
}
__device__ __forceinline__ float siluf(float x) { return x / (1.f + __expf(-x)); }
__device__ __forceinline__ float softplusf(float x) { return x > 20.f ? x : log1pf(__expf(x)); }

// async global->LDS, 16B per lane; LDS dest is wave-uniform base + lane*16
__device__ __forceinline__ void gl2lds16(const void* g, void* l) {
  __builtin_amdgcn_global_load_lds((const __attribute__((address_space(1))) void*)g,
                                   (__attribute__((address_space(3))) void*)l, 16, 0, 0);
}

// ---------------------------------------------------------------------------
// Fused f32 -> bf16 conversion, 5 flat weight tensors.
// ---------------------------------------------------------------------------
struct CvtArgs {
  const float* src[5];
  __bf16*      dst[5];
  int nblk[6];
};

__global__ __launch_bounds__(256) void cvt_bf16_kernel(CvtArgs a) {
  int blk = blockIdx.x;
  int seg = 0;
#pragma unroll
  for (int s = 1; s < 5; s++) if (blk >= a.nblk[s]) seg = s;
  size_t base = (size_t)(blk - a.nblk[seg]) * 2048 + threadIdx.x * 8;
  const float* src = a.src[seg] + base;
  __bf16*      dst = a.dst[seg] + base;
  float4 v0 = *(const float4*)src;
  float4 v1 = *(const float4*)(src + 4);
  union { __bf16 b[8]; uint4 u; } t;
  t.b[0]=f2bf(v0.x); t.b[1]=f2bf(v0.y); t.b[2]=f2bf(v0.z); t.b[3]=f2bf(v0.w);
  t.b[4]=f2bf(v1.x); t.b[5]=f2bf(v1.y); t.b[6]=f2bf(v1.z); t.b[7]=f2bf(v1.w);
  *(uint4*)dst = t.u;
}

// w1,w2 -> packed b_w12: 16-row interleave. dst row (r>>4)*32 + (r&15) + 16*isw2.
__global__ __launch_bounds__(256) void cvt_w12_kernel(const float* __restrict__ w1,
                                                      const float* __restrict__ w2,
                                                      __bf16* __restrict__ dst) {
  int blk = blockIdx.x;              // 0..4095
  int isw2 = blk >> 11;
  int b = blk & 2047;                // 2 rows per block
  int r = b * 2 + (threadIdx.x >> 7);
  int col = (threadIdx.x & 127) * 8;
  const float* src = (isw2 ? w2 : w1) + (size_t)r * DM + col;
  int dr = (r >> 4) * 32 + (r & 15) + isw2 * 16;
  float4 v0 = *(const float4*)src;
  float4 v1 = *(const float4*)(src + 4);
  union { __bf16 b[8]; uint4 u; } t;
  t.b[0]=f2bf(v0.x); t.b[1]=f2bf(v0.y); t.b[2]=f2bf(v0.z); t.b[3]=f2bf(v0.w);
  t.b[4]=f2bf(v1.x); t.b[5]=f2bf(v1.y); t.b[6]=f2bf(v1.z); t.b[7]=f2bf(v1.w);
  *(uint4*)&dst[(size_t)dr * DM + col] = t.u;
}

// ---------------------------------------------------------------------------
// RMSNorm: one block per row of 1024 f32, output bf16.
// ---------------------------------------------------------------------------
__global__ __launch_bounds__(256) void rmsnorm_kernel(const float* __restrict__ x,
                                                      const float* __restrict__ w,
                                                      __bf16* __restrict__ out) {
  int row = blockIdx.x;
  const float* xr = x + (size_t)row * DM;
  float4 v = ((const float4*)xr)[threadIdx.x];
  float ss = v.x*v.x + v.y*v.y + v.z*v.z + v.w*v.w;
#pragma unroll
  for (int o = 32; o > 0; o >>= 1) ss += __shfl_xor(ss, o);
  __shared__ float sred[4];
  if ((threadIdx.x & 63) == 0) sred[threadIdx.x >> 6] = ss;
  __syncthreads();
  float tot = sred[0] + sred[1] + sred[2] + sred[3];
  float scale = rsqrtf(tot * (1.f / DM) + 1e-5f);
  float4 wv = ((const float4*)w)[threadIdx.x];
  union { __bf16 b[4]; ushort4 u; } o;
  o.b[0] = f2bf(v.x * scale * wv.x);
  o.b[1] = f2bf(v.y * scale * wv.y);
  o.b[2] = f2bf(v.z * scale * wv.z);
  o.b[3] = f2bf(v.w * scale * wv.w);
  *(ushort4*)&out[(size_t)row * DM + threadIdx.x * 4] = o.u;
}

// ---------------------------------------------------------------------------
// GEMM: C[M,N] = A[M,K] @ B[N,K]^T, BN=128, BK=32, 4 waves.
// Software-pipelined K-loop: LDS double-buffer, next-tile DMA issued before
// a PARTIAL s_waitcnt vmcnt(N) + raw s_barrier (prefetch stays in flight).
// Staging: r3 quad-contiguous map (lane>>2 row, 64B per quad), row-major LDS.
// EPI: 1 bf16, 2 softplus(acc+bias[col]) f32, 3 acc+aux f32,
//      5 atomicAdd f32 (split-K), 6 packed-SwiGLU: silu(acc[j-1])*acc[j] bf16
// ---------------------------------------------------------------------------
template<int BM, int A_F32, int EPI>
__global__ __launch_bounds__(256) void gemm2(
    const void* __restrict__ Ap, const __bf16* __restrict__ Bp,
    void* __restrict__ Cp, const void* __restrict__ auxp,
    int N, int K, int lda, int ldb, int ldc)
{
  constexpr int FM = BM / 32;          // frag rows per wave
  constexpr int AI = BM / 64;          // A staging instrs per wave
  __shared__ __bf16 sA[2][BM * 32];
  __shared__ __bf16 sB[2][128 * 32];
  const int tid  = threadIdx.x;
  const int wave = tid >> 6, lane = tid & 63;
  const int m0 = blockIdx.y * BM, n0 = blockIdx.x * 128;
  const int wr = wave >> 1, wc = wave & 1;
  const int frow = lane & 15, fq = lane >> 4;

  f32x4 acc[FM][4] = {};

  const int kPer = K / (int)gridDim.z;
  const int kBeg = blockIdx.z * kPer, kEnd = kBeg + kPer;

  const int lrow = lane >> 2;          // 4 lanes per 64B row segment
  const int lcol = (lane & 3) * 8;

  auto stage = [&](int kt, int buf) {
#pragma unroll
    for (int q = 0; q < AI; q++) {
      int idx = wave * AI + q;
      gl2lds16((const __bf16*)Ap + (size_t)(m0 + idx * 16 + lrow) * lda + kt + lcol,
               &sA[buf][idx * 512]);
    }
#pragma unroll
    for (int q = 0; q < 2; q++) {
      int idx = wave * 2 + q;
      gl2lds16(Bp + (size_t)(n0 + idx * 16 + lrow) * ldb + kt + lcol,
               &sB[buf][idx * 512]);
    }
  };

  if (!A_F32) {
    stage(kBeg, 0);
    int cur = 0;
    for (int kt = kBeg; kt < kEnd; kt += 32) {
      int knext = (kt + 32 < kEnd) ? kt + 32 : kBeg;   // wrap: keeps vmcnt constant
      asm volatile("s_waitcnt lgkmcnt(0)" ::: "memory");
      __builtin_amdgcn_s_barrier();                    // safe to overwrite buf[cur^1]
      stage(knext, cur ^ 1);
      if constexpr (AI + 2 == 4) asm volatile("s_waitcnt vmcnt(4)" ::: "memory");
      else                       asm volatile("s_waitcnt vmcnt(3)" ::: "memory");
      __builtin_amdgcn_s_barrier();                    // buf[cur] ready for all waves
      bf16x8 afr[FM], bfr[4];
#pragma unroll
      for (int i = 0; i < FM; i++)
        afr[i] = *(const bf16x8*)&sA[cur][(wr * (BM/2) + i * 16 + frow) * 32 + fq * 8];
#pragma unroll
      for (int j = 0; j < 4; j++)
        bfr[j] = *(const bf16x8*)&sB[cur][(wc * 64 + j * 16 + frow) * 32 + fq * 8];
#pragma unroll
      for (int i = 0; i < FM; i++)
#pragma unroll
        for (int j = 0; j < 4; j++)
          acc[i][j] = __builtin_amdgcn_mfma_f32_16x16x32_bf16(afr[i], bfr[j], acc[i][j], 0, 0, 0);
      cur ^= 1;
    }
  } else {
    // dt-GEMM only (K=64): simple single-buffer, f32 A converted in VGPRs
    for (int kt = kBeg; kt < kEnd; kt += 32) {
      int srow = tid >> 1, sh = (tid & 1) * 16;
      const float* src = (const float*)Ap + (size_t)(m0 + srow) * lda + kt + sh;
      union { __bf16 b[16]; uint4 u[2]; } t;
#pragma unroll
      for (int q = 0; q < 4; q++) {
        float4 v = *(const float4*)(src + q * 4);
        t.b[q*4+0]=f2bf(v.x); t.b[q*4+1]=f2bf(v.y); t.b[q*4+2]=f2bf(v.z); t.b[q*4+3]=f2bf(v.w);
      }
      *(uint4*)&sA[0][srow * 32 + sh]     = t.u[0];
      *(uint4*)&sA[0][srow * 32 + sh + 8] = t.u[1];
#pragma unroll
      for (int q = 0; q < 2; q++) {
        int idx = wave * 2 + q;
        gl2lds16(Bp + (size_t)(n0 + idx * 16 + lrow) * ldb + kt + lcol, &sB[0][idx * 512]);
      }
      __syncthreads();
      bf16x8 afr[FM], bfr[4];
#pragma unroll
      for (int i = 0; i < FM; i++)
        afr[i] = *(const bf16x8*)&sA[0][(wr * (BM/2) + i * 16 + frow) * 32 + fq * 8];
#pragma unroll
      for (int j = 0; j < 4; j++)
        bfr[j] = *(const bf16x8*)&sB[0][(wc * 64 + j * 16 + frow) * 32 + fq * 8];
#pragma unroll
      for (int i = 0; i < FM; i++)
#pragma unroll
        for (int j = 0; j < 4; j++)
          acc[i][j] = __builtin_amdgcn_mfma_f32_16x16x32_bf16(afr[i], bfr[j], acc[i][j], 0, 0, 0);
      __syncthreads();
    }
  }

  const float*  auxf = (const float*)auxp;
#pragma unroll
  for (int i = 0; i < FM; i++) {
    int gr = m0 + wr * (BM/2) + i * 16 + fq * 4;
#pragma unroll
    for (int j = 0; j < 4; j++) {
      int gc = n0 + wc * 64 + j * 16 + frow;
#pragma unroll
      for (int r = 0; r < 4; r++) {
        float v = acc[i][j][r];
        if (EPI == 6) {
          if (j & 1) {
            int col = (n0 >> 1) + 32 * wc + 16 * (j >> 1) + frow;
            size_t off = (size_t)(gr + r) * ldc + col;
            float g = acc[i][j-1][r];
            ((__bf16*)Cp)[off] = f2bf(siluf(g) * v);
          }
        } else {
          size_t off = (size_t)(gr + r) * ldc + gc;
          if (EPI == 1) ((__bf16*)Cp)[off] = f2bf(v);
          else if (EPI == 2) ((float*)Cp)[off] = softplusf(v + auxf[gc]);
          else if (EPI == 3) ((float*)Cp)[off] = v + auxf[off];
          else if (EPI == 5) atomicAdd((float*)Cp + off, v);
        }
      }
    }
  }
  (void)N;
}

// ---------------------------------------------------------------------------
// Causal depthwise conv (width 4) + SiLU.
// ---------------------------------------------------------------------------
__global__ __launch_bounds__(256) void conv_silu_kernel(const __bf16* __restrict__ xz,
                                                        const float* __restrict__ cw,
                                                        const float* __restrict__ cb,
                                                        __bf16* __restrict__ uact) {
  int idx = blockIdx.x * 256 + threadIdx.x;
  int d   = idx & (DI - 1);
  int tok = idx >> 11;
  int l   = tok & 2047;
  float4 wv = *(const float4*)(cw + d * 4);
  const __bf16* up = xz + (size_t)tok * (2 * DI) + d;
  float acc = cb[d];
  if (l >= 3) acc += wv.x * (float)up[-3 * (2 * DI)];
  if (l >= 2) acc += wv.y * (float)up[-2 * (2 * DI)];
  if (l >= 1) acc += wv.z * (float)up[-1 * (2 * DI)];
  acc += wv.w * (float)up[0];
  uact[idx] = f2bf(siluf(acc));
}

// ---------------------------------------------------------------------------
// Selective scan, chunked 2-pass linear recurrence (proj stride = PROJ_LD).
// ---------------------------------------------------------------------------
__global__ __launch_bounds__(64) void scan_pass1(const float* __restrict__ dt,
                                                 const __bf16* __restrict__ uact,
                                                 const float* __restrict__ proj,
                                                 const float* __restrict__ A_log,
                                                 float* __restrict__ aprod,
                                                 float* __restrict__ hend) {
  int lane = threadIdx.x;
  int d = blockIdx.x * 64 + lane;
  int c = blockIdx.y, b = blockIdx.z;
  float An[16], h[16], ap[16];
  {
    const float4* a4 = (const float4*)(A_log + (size_t)d * 16);
#pragma unroll
    for (int q = 0; q < 4; q++) {
      float4 v = a4[q];
      An[q*4+0] = -__expf(v.x); An[q*4+1] = -__expf(v.y);
      An[q*4+2] = -__expf(v.z); An[q*4+3] = -__expf(v.w);
    }
  }
#pragma unroll
  for (int n = 0; n < 16; n++) { h[n] = 0.f; ap[n] = 1.f; }

  size_t tok = (size_t)b * 2048 + (size_t)c * CHUNK;
  const float*  dtp = dt   + tok * DI + d;
  const __bf16* up  = uact + tok * DI + d;
  const float*  pp  = proj + tok * PROJ_LD;

  for (int t = 0; t < CHUNK; t++) {
    float dtv = *dtp;
    float uv  = (float)*up;
    const float4* b4 = (const float4*)(pp + 64);
    float Bv[16];
#pragma unroll
    for (int q = 0; q < 4; q++) {
      float4 v = b4[q];
      Bv[q*4+0]=v.x; Bv[q*4+1]=v.y; Bv[q*4+2]=v.z; Bv[q*4+3]=v.w;
    }
    float du = dtv * uv;
#pragma unroll
    for (int n = 0; n < 16; n++) {
      float dA = __expf(dtv * An[n]);
      ap[n] *= dA;
      h[n] = fmaf(dA, h[n], du * Bv[n]);
    }
    dtp += DI; up += DI; pp += PROJ_LD;
  }

  size_t off = ((size_t)(b * NC + c) * DI + d) * 16;
#pragma unroll
  for (int q = 0; q < 4; q++) {
    *(float4*)(hend  + off + q*4) = make_float4(h[q*4+0],  h[q*4+1],  h[q*4+2],  h[q*4+3]);
    *(float4*)(aprod + off + q*4) = make_float4(ap[q*4+0], ap[q*4+1], ap[q*4+2], ap[q*4+3]);
  }
}

__global__ __launch_bounds__(256) void scan_pass2(const float* __restrict__ aprod,
                                                  const float* __restrict__ hend,
                                                  float* __restrict__ hstart) {
  int idx = blockIdx.x * 256 + threadIdx.x;
  int b  = idx >> 13;
  int r4 = idx & 8191;
  float4 H = make_float4(0.f, 0.f, 0.f, 0.f);
  for (int c = 0; c < NC; c++) {
    size_t off = (size_t)(b * NC + c) * (DI * 16 / 4) + r4;
    ((float4*)hstart)[off] = H;
    float4 a = ((const float4*)aprod)[off];
    float4 e = ((const float4*)hend)[off];
    H.x = fmaf(a.x, H.x, e.x);
    H.y = fmaf(a.y, H.y, e.y);
    H.z = fmaf(a.z, H.z, e.z);
    H.w = fmaf(a.w, H.w, e.w);
  }
}

__global__ __launch_bounds__(64) void scan_pass3(const float* __restrict__ dt,
                                                 const __bf16* __restrict__ uact,
                                                 const float* __restrict__ proj,
                                                 const __bf16* __restrict__ xz,
                                                 const float* __restrict__ A_log,
                                                 const float* __restrict__ Dp,
                                                 const float* __restrict__ hstart,
                                                 __bf16* __restrict__ y) {
  int lane = threadIdx.x;
  int d = blockIdx.x * 64 + lane;
  int c = blockIdx.y, b = blockIdx.z;
  float An[16], h[16];
  {
    const float4* a4 = (const float4*)(A_log + (size_t)d * 16);
#pragma unroll
    for (int q = 0; q < 4; q++) {
      float4 v = a4[q];
      An[q*4+0] = -__expf(v.x); An[q*4+1] = -__expf(v.y);
      An[q*4+2] = -__expf(v.z); An[q*4+3] = -__expf(v.w);
    }
  }
  {
    size_t off = ((size_t)(b * NC + c) * DI + d) * 16;
#pragma unroll
    for (int q = 0; q < 4; q++) {
      float4 v = *(const float4*)(hstart + off + q*4);
      h[q*4+0]=v.x; h[q*4+1]=v.y; h[q*4+2]=v.z; h[q*4+3]=v.w;
    }
  }
  float Dd = Dp[d];

  size_t tok = (size_t)b * 2048 + (size_t)c * CHUNK;
  const float*  dtp = dt   + tok * DI + d;
  const __bf16* up  = uact + tok * DI + d;
  const float*  pp  = proj + tok * PROJ_LD;
  const __bf16* zp  = xz   + tok * (2 * DI) + DI + d;
  __bf16*       yp  = y    + tok * DI + d;

  for (int t = 0; t < CHUNK; t++) {
    float dtv = *dtp;
    float uv  = (float)*up;
    float zv  = (float)*zp;
    const float4* b4 = (const float4*)(pp + 64);
    float Bv[16], Cv[16];
#pragma unroll
    for (int q = 0; q < 4; q++) {
      float4 v = b4[q];
      Bv[q*4+0]=v.x; Bv[q*4+1]=v.y; Bv[q*4+2]=v.z; Bv[q*4+3]=v.w;
      float4 w = b4[q + 4];
      Cv[q*4+0]=w.x; Cv[q*4+1]=w.y; Cv[q*4+2]=w.z; Cv[q*4+3]=w.w;
    }
    float du = dtv * uv;
    float p = 0.f;
#pragma unroll
    for (int n = 0; n < 16; n++) {
      float dA = __expf(dtv * An[n]);
      h[n] = fmaf(dA, h[n], du * Bv[n]);
      p = fmaf(h[n], Cv[n], p);
    }
    *yp = f2bf((p + Dd * uv) * siluf(zv));
    dtp += DI; up += DI; pp += PROJ_LD; zp += 2 * DI; yp += DI;
  }
}

// ---------------------------------------------------------------------------
extern "C" void kernel_launch(void* const* d_in, const int* in_sizes, int n_in,
                              void* d_out, int out_size, void* d_ws, size_t ws_size,
                              hipStream_t stream) {
  const float* x        = (const float*)d_in[0];
  const float* n1w      = (const float*)d_in[1];
  const float* n2w      = (const float*)d_in[2];
  const float* in_projw = (const float*)d_in[3];
  const float* conv_w   = (const float*)d_in[4];
  const float* conv_b   = (const float*)d_in[5];
  const float* x_projw  = (const float*)d_in[6];
  const float* dt_projw = (const float*)d_in[7];
  const float* dt_projb = (const float*)d_in[8];
  const float* A_log    = (const float*)d_in[9];
  const float* Dp       = (const float*)d_in[10];
  const float* out_projw= (const float*)d_in[11];
  const float* w1       = (const float*)d_in[12];
  const float* w2       = (const float*)d_in[13];
  const float* w3       = (const float*)d_in[14];
  float* out = (float*)d_out;

  char* ws = (char*)d_ws;
  __bf16* xz   = (__bf16*)(ws + 0);            // 4096x4096 bf16 = 33554432
  __bf16* uact = (__bf16*)(ws + 33554432);     // 4096x2048 bf16 = 16777216
  float*  proj = (float*) (ws + 50331648);     // 4096x128 f32  =  2097152
  float*  dt   = (float*) (ws + 52428800);     // 4096x2048 f32 = 33554432
  __bf16* yb   = (__bf16*)(ws + 85983232);     // 4096x2048 bf16= 16777216
  float*  h    = (float*) (ws + 102760448);    // 4096x1024 f32 = 16777216
  __bf16* xn   = (__bf16*)(ws + 119537664);    // 4096x1024 bf16=  8388608
  __bf16* hid  = (__bf16*)dt;                  // union: reused after scan
  float* aprod  = (float*)(ws + 102760448);    // overlaps h (dead until step 7)
  float* hend   = (float*)(ws + 111149056);
  float* hstart = (float*)(ws + 119537664);    // overlaps xn
  char* wb = ws + 127926272;
  __bf16* b_in  = (__bf16*)(wb);               // 8388608
  __bf16* b_xp  = (__bf16*)(wb + 8388608);     // 128x2048 (padded) = 524288
  __bf16* b_dtp = (__bf16*)(wb + 8912896);     // 262144
  __bf16* b_out = (__bf16*)(wb + 9175040);     // 4194304
  __bf16* b_w12 = (__bf16*)(wb + 13369344);    // 8192x1024 packed = 16777216
  __bf16* b_w3  = (__bf16*)(wb + 30146560);    // 8388608, end 38535168

  hipMemsetAsync(b_xp, 0, 128 * 2048 * sizeof(__bf16), stream);
  hipMemsetAsync(proj, 0, TOKS * PROJ_LD * sizeof(float), stream);

  CvtArgs ca;
  const float* srcs[5] = {in_projw, x_projw, dt_projw, out_projw, w3};
  __bf16* dsts[5]      = {b_in, b_xp, b_dtp, b_out, b_w3};
  int counts[5] = {4096*1024, 96*2048, 2048*64, 1024*2048, 1024*4096};
  int acc = 0;
  for (int i = 0; i < 5; i++) { ca.src[i] = srcs[i]; ca.dst[i] = dsts[i]; ca.nblk[i] = acc; acc += counts[i] / 2048; }
  ca.nblk[5] = acc;
  cvt_bf16_kernel<<<acc, 256, 0, stream>>>(ca);
  cvt_w12_kernel<<<4096, 256, 0, stream>>>(w1, w2, b_w12);

  dim3 blk(256);
  // 1. xn = rmsnorm(x, norm1_w)
  rmsnorm_kernel<<<TOKS, 256, 0, stream>>>(x, n1w, xn);
  // 2. xz = xn @ in_proj_w.T          (4096x4096, K=1024) -> bf16
  gemm2<128,0,1><<<dim3(32,32,1), blk, 0, stream>>>(xn, b_in, xz, nullptr, 2*DI, DM, DM, DM, 2*DI);
  // 3. u_act = silu(causal_conv(u))   -> bf16
  conv_silu_kernel<<<(TOKS*DI)/256, 256, 0, stream>>>(xz, conv_w, conv_b, uact);
  // 4. proj += u_act @ x_proj_w.T     (4096x128pad, K=2048, split-K x8, atomic)
  gemm2<128,0,5><<<dim3(1,32,8), blk, 0, stream>>>(uact, b_xp, proj, nullptr, PROJ_LD, DI, DI, DI, PROJ_LD);
  // 5. dt = softplus(dt_r @ dt_proj_w.T + b)   (4096x2048, K=64) -> f32
  gemm2<128,1,2><<<dim3(16,32,1), blk, 0, stream>>>(proj, b_dtp, dt, dt_projb, DI, DTR, PROJ_LD, DTR, DI);
  // 6. selective scan (chunked 2-pass) -> y (bf16)
  scan_pass1<<<dim3(DI/64, NC, 2), 64, 0, stream>>>(dt, uact, proj, A_log, aprod, hend);
  scan_pass2<<<64, 256, 0, stream>>>(aprod, hend, hstart);
  scan_pass3<<<dim3(DI/64, NC, 2), 64, 0, stream>>>(dt, uact, proj, xz, A_log, Dp, hstart, yb);
  // 7. h = y @ out_proj_w.T + x       (4096x1024, K=2048) -> f32, BM=64
  gemm2<64,0,3><<<dim3(8,64,1), blk, 0, stream>>>(yb, b_out, h, x, DM, DI, DI, DI, DM);
  // 8. xn = rmsnorm(h, norm2_w)
  rmsnorm_kernel<<<TOKS, 256, 0, stream>>>(h, n2w, xn);
  // 9+10 fused: hid = silu(xn@w1.T) * (xn@w2.T)  (packed N=8192) -> bf16
  gemm2<128,0,6><<<dim3(64,32,1), blk, 0, stream>>>(xn, b_w12, hid, nullptr, 2*DFF, DM, DM, DM, DFF);
  // 11. out = hid @ w3.T + h          (4096x1024, K=4096) -> f32, BM=64
  gemm2<64,0,3><<<dim3(8,64,1), blk, 0, stream>>>(hid, b_w3, out, h, DM, DFF, DFF, DFF, DM);

  (void)in_sizes; (void)n_in; (void)out_size; (void)ws_size;
}

// Round 6
// 599.863 us; speedup vs baseline: 1.2143x; 1.1179x over previous
//
#include <hip/hip_runtime.h>
#include <hip/hip_bf16.h>

// Shapes (fixed): B=2, L=2048 -> TOK=4096 tokens
#define TOKS 4096
#define DM   1024
#define DI   2048
#define DST  16
#define DTR  64
#define DFF  4096
#define PROJ_LD 128   // x_proj output padded 96 -> 128

// scan chunking
#define NC    32
#define CHUNK 64

typedef __bf16 bf16x8 __attribute__((ext_vector_type(8)));
typedef float  f32x4  __attribute__((ext_vector_type(4)));

__device__ __forceinline__ __bf16 f2bf(float f) {
  union { float f; unsigned u; } v; v.f = f;
  unsigned r = v.u + 0x7fffu + ((v.u >> 16) & 1u);
  union { unsigned short s; __bf16 b; } o; o.s = (unsigned short)(r >> 16);
  return o.b;
}
__device__ __forceinline__ float siluf(float x) { return x / (1.f + __expf(-x)); }
__device__ __forceinline__ float softplusf(float x) { return x > 20.f ? x : log1pf(__expf(x)); }

// async global->LDS, 16B per lane; LDS dest is wave-uniform base + lane*16
__device__ __forceinline__ void gl2lds16(const void* g, void* l) {
  __builtin_amdgcn_global_load_lds((const __attribute__((address_space(1))) void*)g,
                                   (__attribute__((address_space(3))) void*)l, 16, 0, 0);
}

// ---------------------------------------------------------------------------
// Fused f32 -> bf16 conversion, 5 flat weight tensors.
// ---------------------------------------------------------------------------
struct CvtArgs {
  const float* src[5];
  __bf16*      dst[5];
  int nblk[6];
};

__global__ __launch_bounds__(256) void cvt_bf16_kernel(CvtArgs a) {
  int blk = blockIdx.x;
  int seg = 0;
#pragma unroll
  for (int s = 1; s < 5; s++) if (blk >= a.nblk[s]) seg = s;
  size_t base = (size_t)(blk - a.nblk[seg]) * 2048 + threadIdx.x * 8;
  const float* src = a.src[seg] + base;
  __bf16*      dst = a.dst[seg] + base;
  float4 v0 = *(const float4*)src;
  float4 v1 = *(const float4*)(src + 4);
  union { __bf16 b[8]; uint4 u; } t;
  t.b[0]=f2bf(v0.x); t.b[1]=f2bf(v0.y); t.b[2]=f2bf(v0.z); t.b[3]=f2bf(v0.w);
  t.b[4]=f2bf(v1.x); t.b[5]=f2bf(v1.y); t.b[6]=f2bf(v1.z); t.b[7]=f2bf(v1.w);
  *(uint4*)dst = t.u;
}

// w1,w2 -> packed b_w12: 16-row interleave. dst row (r>>4)*32 + (r&15) + 16*isw2.
__global__ __launch_bounds__(256) void cvt_w12_kernel(const float* __restrict__ w1,
                                                      const float* __restrict__ w2,
                                                      __bf16* __restrict__ dst) {
  int blk = blockIdx.x;              // 0..4095
  int isw2 = blk >> 11;
  int b = blk & 2047;                // 2 rows per block
  int r = b * 2 + (threadIdx.x >> 7);
  int col = (threadIdx.x & 127) * 8;
  const float* src = (isw2 ? w2 : w1) + (size_t)r * DM + col;
  int dr = (r >> 4) * 32 + (r & 15) + isw2 * 16;
  float4 v0 = *(const float4*)src;
  float4 v1 = *(const float4*)(src + 4);
  union { __bf16 b[8]; uint4 u; } t;
  t.b[0]=f2bf(v0.x); t.b[1]=f2bf(v0.y); t.b[2]=f2bf(v0.z); t.b[3]=f2bf(v0.w);
  t.b[4]=f2bf(v1.x); t.b[5]=f2bf(v1.y); t.b[6]=f2bf(v1.z); t.b[7]=f2bf(v1.w);
  *(uint4*)&dst[(size_t)dr * DM + col] = t.u;
}

// ---------------------------------------------------------------------------
// RMSNorm: one block per row of 1024 f32, output bf16.
// ---------------------------------------------------------------------------
__global__ __launch_bounds__(256) void rmsnorm_kernel(const float* __restrict__ x,
                                                      const float* __restrict__ w,
                                                      __bf16* __restrict__ out) {
  int row = blockIdx.x;
  const float* xr = x + (size_t)row * DM;
  float4 v = ((const float4*)xr)[threadIdx.x];
  float ss = v.x*v.x + v.y*v.y + v.z*v.z + v.w*v.w;
#pragma unroll
  for (int o = 32; o > 0; o >>= 1) ss += __shfl_xor(ss, o);
  __shared__ float sred[4];
  if ((threadIdx.x & 63) == 0) sred[threadIdx.x >> 6] = ss;
  __syncthreads();
  float tot = sred[0] + sred[1] + sred[2] + sred[3];
  float scale = rsqrtf(tot * (1.f / DM) + 1e-5f);
  float4 wv = ((const float4*)w)[threadIdx.x];
  union { __bf16 b[4]; ushort4 u; } o;
  o.b[0] = f2bf(v.x * scale * wv.x);
  o.b[1] = f2bf(v.y * scale * wv.y);
  o.b[2] = f2bf(v.z * scale * wv.z);
  o.b[3] = f2bf(v.w * scale * wv.w);
  *(ushort4*)&out[(size_t)row * DM + threadIdx.x * 4] = o.u;
}

// ---------------------------------------------------------------------------
// GEMM: C[M,N] = A[M,K] @ B[N,K]^T, BN=128, BK=32, 4 waves, single-buffered
// (r3-proven structure: global_load_lds width=16, quad-contiguous staging,
// compiler-managed waitcnt + __syncthreads).
// SWAP=1: blockIdx.x indexes M (fast dim) so blocks sharing an A-slice land
// on the SAME XCD (id mod 8 preserved) -> A becomes L2-resident for deep-K
// narrow-N GEMMs (out_proj, w3).
// EPI: 1 bf16, 2 softplus(acc+bias[col]) f32, 3 acc+aux f32,
//      5 atomicAdd f32 (split-K), 6 packed-SwiGLU: silu(acc[j-1])*acc[j] bf16
// ---------------------------------------------------------------------------
template<int BM, int A_F32, int EPI, int SWAP>
__global__ __launch_bounds__(256) void gemm2(
    const void* __restrict__ Ap, const __bf16* __restrict__ Bp,
    void* __restrict__ Cp, const void* __restrict__ auxp,
    int N, int K, int lda, int ldb, int ldc)
{
  constexpr int FM = BM / 32;          // frag rows per wave
  constexpr int AI = BM / 64;          // A staging instrs per wave
  __shared__ __bf16 sA[BM * 32];
  __shared__ __bf16 sB[128 * 32];
  const int tid  = threadIdx.x;
  const int wave = tid >> 6, lane = tid & 63;
  const int bm = SWAP ? blockIdx.x : blockIdx.y;
  const int bn = SWAP ? blockIdx.y : blockIdx.x;
  const int m0 = bm * BM, n0 = bn * 128;
  const int wr = wave >> 1, wc = wave & 1;
  const int frow = lane & 15, fq = lane >> 4;

  f32x4 acc[FM][4] = {};

  const int kPer = K / (int)gridDim.z;
  const int kBeg = blockIdx.z * kPer, kEnd = kBeg + kPer;

  const int lrow = lane >> 2;          // 4 lanes per 64B row segment
  const int lcol = (lane & 3) * 8;

  for (int kt = kBeg; kt < kEnd; kt += 32) {
    if (A_F32) {
      int srow = tid >> 1, sh = (tid & 1) * 16;
      const float* src = (const float*)Ap + (size_t)(m0 + srow) * lda + kt + sh;
      union { __bf16 b[16]; uint4 u[2]; } t;
#pragma unroll
      for (int q = 0; q < 4; q++) {
        float4 v = *(const float4*)(src + q * 4);
        t.b[q*4+0]=f2bf(v.x); t.b[q*4+1]=f2bf(v.y); t.b[q*4+2]=f2bf(v.z); t.b[q*4+3]=f2bf(v.w);
      }
      *(uint4*)&sA[srow * 32 + sh]     = t.u[0];
      *(uint4*)&sA[srow * 32 + sh + 8] = t.u[1];
    } else {
#pragma unroll
      for (int q = 0; q < AI; q++) {
        int idx = wave * AI + q;
        gl2lds16((const __bf16*)Ap + (size_t)(m0 + idx * 16 + lrow) * lda + kt + lcol,
                 &sA[idx * 512]);
      }
    }
#pragma unroll
    for (int q = 0; q < 2; q++) {
      int idx = wave * 2 + q;
      gl2lds16(Bp + (size_t)(n0 + idx * 16 + lrow) * ldb + kt + lcol, &sB[idx * 512]);
    }
    __syncthreads();

    bf16x8 afr[FM], bfr[4];
#pragma unroll
    for (int i = 0; i < FM; i++)
      afr[i] = *(const bf16x8*)&sA[(wr * (BM/2) + i * 16 + frow) * 32 + fq * 8];
#pragma unroll
    for (int j = 0; j < 4; j++)
      bfr[j] = *(const bf16x8*)&sB[(wc * 64 + j * 16 + frow) * 32 + fq * 8];
#pragma unroll
    for (int i = 0; i < FM; i++)
#pragma unroll
      for (int j = 0; j < 4; j++)
        acc[i][j] = __builtin_amdgcn_mfma_f32_16x16x32_bf16(afr[i], bfr[j], acc[i][j], 0, 0, 0);
    __syncthreads();
  }

  const float*  auxf = (const float*)auxp;
#pragma unroll
  for (int i = 0; i < FM; i++) {
    int gr = m0 + wr * (BM/2) + i * 16 + fq * 4;
#pragma unroll
    for (int j = 0; j < 4; j++) {
      int gc = n0 + wc * 64 + j * 16 + frow;
#pragma unroll
      for (int r = 0; r < 4; r++) {
        float v = acc[i][j][r];
        if (EPI == 6) {
          if (j & 1) {
            int col = (n0 >> 1) + 32 * wc + 16 * (j >> 1) + frow;
            size_t off = (size_t)(gr + r) * ldc + col;
            float g = acc[i][j-1][r];
            ((__bf16*)Cp)[off] = f2bf(siluf(g) * v);
          }
        } else {
          size_t off = (size_t)(gr + r) * ldc + gc;
          if (EPI == 1) ((__bf16*)Cp)[off] = f2bf(v);
          else if (EPI == 2) ((float*)Cp)[off] = softplusf(v + auxf[gc]);
          else if (EPI == 3) ((float*)Cp)[off] = v + auxf[off];
          else if (EPI == 5) atomicAdd((float*)Cp + off, v);
        }
      }
    }
  }
  (void)N;
}

// ---------------------------------------------------------------------------
// Causal depthwise conv (width 4) + SiLU.
// ---------------------------------------------------------------------------
__global__ __launch_bounds__(256) void conv_silu_kernel(const __bf16* __restrict__ xz,
                                                        const float* __restrict__ cw,
                                                        const float* __restrict__ cb,
                                                        __bf16* __restrict__ uact) {
  int idx = blockIdx.x * 256 + threadIdx.x;
  int d   = idx & (DI - 1);
  int tok = idx >> 11;
  int l   = tok & 2047;
  float4 wv = *(const float4*)(cw + d * 4);
  const __bf16* up = xz + (size_t)tok * (2 * DI) + d;
  float acc = cb[d];
  if (l >= 3) acc += wv.x * (float)up[-3 * (2 * DI)];
  if (l >= 2) acc += wv.y * (float)up[-2 * (2 * DI)];
  if (l >= 1) acc += wv.z * (float)up[-1 * (2 * DI)];
  acc += wv.w * (float)up[0];
  uact[idx] = f2bf(siluf(acc));
}

// ---------------------------------------------------------------------------
// Selective scan, chunked 2-pass linear recurrence (proj stride = PROJ_LD).
// ---------------------------------------------------------------------------
__global__ __launch_bounds__(64) void scan_pass1(const float* __restrict__ dt,
                                                 const __bf16* __restrict__ uact,
                                                 const float* __restrict__ proj,
                                                 const float* __restrict__ A_log,
                                                 float* __restrict__ aprod,
                                                 float* __restrict__ hend) {
  int lane = threadIdx.x;
  int d = blockIdx.x * 64 + lane;
  int c = blockIdx.y, b = blockIdx.z;
  float An[16], h[16], ap[16];
  {
    const float4* a4 = (const float4*)(A_log + (size_t)d * 16);
#pragma unroll
    for (int q = 0; q < 4; q++) {
      float4 v = a4[q];
      An[q*4+0] = -__expf(v.x); An[q*4+1] = -__expf(v.y);
      An[q*4+2] = -__expf(v.z); An[q*4+3] = -__expf(v.w);
    }
  }
#pragma unroll
  for (int n = 0; n < 16; n++) { h[n] = 0.f; ap[n] = 1.f; }

  size_t tok = (size_t)b * 2048 + (size_t)c * CHUNK;
  const float*  dtp = dt   + tok * DI + d;
  const __bf16* up  = uact + tok * DI + d;
  const float*  pp  = proj + tok * PROJ_LD;

  for (int t = 0; t < CHUNK; t++) {
    float dtv = *dtp;
    float uv  = (float)*up;
    const float4* b4 = (const float4*)(pp + 64);
    float Bv[16];
#pragma unroll
    for (int q = 0; q < 4; q++) {
      float4 v = b4[q];
      Bv[q*4+0]=v.x; Bv[q*4+1]=v.y; Bv[q*4+2]=v.z; Bv[q*4+3]=v.w;
    }
    float du = dtv * uv;
#pragma unroll
    for (int n = 0; n < 16; n++) {
      float dA = __expf(dtv * An[n]);
      ap[n] *= dA;
      h[n] = fmaf(dA, h[n], du * Bv[n]);
    }
    dtp += DI; up += DI; pp += PROJ_LD;
  }

  size_t off = ((size_t)(b * NC + c) * DI + d) * 16;
#pragma unroll
  for (int q = 0; q < 4; q++) {
    *(float4*)(hend  + off + q*4) = make_float4(h[q*4+0],  h[q*4+1],  h[q*4+2],  h[q*4+3]);
    *(float4*)(aprod + off + q*4) = make_float4(ap[q*4+0], ap[q*4+1], ap[q*4+2], ap[q*4+3]);
  }
}

__global__ __launch_bounds__(256) void scan_pass2(const float* __restrict__ aprod,
                                                  const float* __restrict__ hend,
                                                  float* __restrict__ hstart) {
  int idx = blockIdx.x * 256 + threadIdx.x;
  int b  = idx >> 13;
  int r4 = idx & 8191;
  float4 H = make_float4(0.f, 0.f, 0.f, 0.f);
  for (int c = 0; c < NC; c++) {
    size_t off = (size_t)(b * NC + c) * (DI * 16 / 4) + r4;
    ((float4*)hstart)[off] = H;
    float4 a = ((const float4*)aprod)[off];
    float4 e = ((const float4*)hend)[off];
    H.x = fmaf(a.x, H.x, e.x);
    H.y = fmaf(a.y, H.y, e.y);
    H.z = fmaf(a.z, H.z, e.z);
    H.w = fmaf(a.w, H.w, e.w);
  }
}

__global__ __launch_bounds__(64) void scan_pass3(const float* __restrict__ dt,
                                                 const __bf16* __restrict__ uact,
                                                 const float* __restrict__ proj,
                                                 const __bf16* __restrict__ xz,
                                                 const float* __restrict__ A_log,
                                                 const float* __restrict__ Dp,
                                                 const float* __restrict__ hstart,
                                                 __bf16* __restrict__ y) {
  int lane = threadIdx.x;
  int d = blockIdx.x * 64 + lane;
  int c = blockIdx.y, b = blockIdx.z;
  float An[16], h[16];
  {
    const float4* a4 = (const float4*)(A_log + (size_t)d * 16);
#pragma unroll
    for (int q = 0; q < 4; q++) {
      float4 v = a4[q];
      An[q*4+0] = -__expf(v.x); An[q*4+1] = -__expf(v.y);
      An[q*4+2] = -__expf(v.z); An[q*4+3] = -__expf(v.w);
    }
  }
  {
    size_t off = ((size_t)(b * NC + c) * DI + d) * 16;
#pragma unroll
    for (int q = 0; q < 4; q++) {
      float4 v = *(const float4*)(hstart + off + q*4);
      h[q*4+0]=v.x; h[q*4+1]=v.y; h[q*4+2]=v.z; h[q*4+3]=v.w;
    }
  }
  float Dd = Dp[d];

  size_t tok = (size_t)b * 2048 + (size_t)c * CHUNK;
  const float*  dtp = dt   + tok * DI + d;
  const __bf16* up  = uact + tok * DI + d;
  const float*  pp  = proj + tok * PROJ_LD;
  const __bf16* zp  = xz   + tok * (2 * DI) + DI + d;
  __bf16*       yp  = y    + tok * DI + d;

  for (int t = 0; t < CHUNK; t++) {
    float dtv = *dtp;
    float uv  = (float)*up;
    float zv  = (float)*zp;
    const float4* b4 = (const float4*)(pp + 64);
    float Bv[16], Cv[16];
#pragma unroll
    for (int q = 0; q < 4; q++) {
      float4 v = b4[q];
      Bv[q*4+0]=v.x; Bv[q*4+1]=v.y; Bv[q*4+2]=v.z; Bv[q*4+3]=v.w;
      float4 w = b4[q + 4];
      Cv[q*4+0]=w.x; Cv[q*4+1]=w.y; Cv[q*4+2]=w.z; Cv[q*4+3]=w.w;
    }
    float du = dtv * uv;
    float p = 0.f;
#pragma unroll
    for (int n = 0; n < 16; n++) {
      float dA = __expf(dtv * An[n]);
      h[n] = fmaf(dA, h[n], du * Bv[n]);
      p = fmaf(h[n], Cv[n], p);
    }
    *yp = f2bf((p + Dd * uv) * siluf(zv));
    dtp += DI; up += DI; pp += PROJ_LD; zp += 2 * DI; yp += DI;
  }
}

// ---------------------------------------------------------------------------
extern "C" void kernel_launch(void* const* d_in, const int* in_sizes, int n_in,
                              void* d_out, int out_size, void* d_ws, size_t ws_size,
                              hipStream_t stream) {
  const float* x        = (const float*)d_in[0];
  const float* n1w      = (const float*)d_in[1];
  const float* n2w      = (const float*)d_in[2];
  const float* in_projw = (const float*)d_in[3];
  const float* conv_w   = (const float*)d_in[4];
  const float* conv_b   = (const float*)d_in[5];
  const float* x_projw  = (const float*)d_in[6];
  const float* dt_projw = (const float*)d_in[7];
  const float* dt_projb = (const float*)d_in[8];
  const float* A_log    = (const float*)d_in[9];
  const float* Dp       = (const float*)d_in[10];
  const float* out_projw= (const float*)d_in[11];
  const float* w1       = (const float*)d_in[12];
  const float* w2       = (const float*)d_in[13];
  const float* w3       = (const float*)d_in[14];
  float* out = (float*)d_out;

  char* ws = (char*)d_ws;
  __bf16* xz   = (__bf16*)(ws + 0);            // 4096x4096 bf16 = 33554432
  __bf16* uact = (__bf16*)(ws + 33554432);     // 4096x2048 bf16 = 16777216
  float*  proj = (float*) (ws + 50331648);     // 4096x128 f32  =  2097152
  float*  dt   = (float*) (ws + 52428800);     // 4096x2048 f32 = 33554432
  __bf16* yb   = (__bf16*)(ws + 85983232);     // 4096x2048 bf16= 16777216
  float*  h    = (float*) (ws + 102760448);    // 4096x1024 f32 = 16777216
  __bf16* xn   = (__bf16*)(ws + 119537664);    // 4096x1024 bf16=  8388608
  __bf16* hid  = (__bf16*)dt;                  // union: reused after scan
  float* aprod  = (float*)(ws + 102760448);    // overlaps h (dead until step 7)
  float* hend   = (float*)(ws + 111149056);
  float* hstart = (float*)(ws + 119537664);    // overlaps xn
  char* wb = ws + 127926272;
  __bf16* b_in  = (__bf16*)(wb);               // 8388608
  __bf16* b_xp  = (__bf16*)(wb + 8388608);     // 128x2048 (padded) = 524288
  __bf16* b_dtp = (__bf16*)(wb + 8912896);     // 262144
  __bf16* b_out = (__bf16*)(wb + 9175040);     // 4194304
  __bf16* b_w12 = (__bf16*)(wb + 13369344);    // 8192x1024 packed = 16777216
  __bf16* b_w3  = (__bf16*)(wb + 30146560);    // 8388608, end 38535168

  hipMemsetAsync(b_xp, 0, 128 * 2048 * sizeof(__bf16), stream);
  hipMemsetAsync(proj, 0, TOKS * PROJ_LD * sizeof(float), stream);

  CvtArgs ca;
  const float* srcs[5] = {in_projw, x_projw, dt_projw, out_projw, w3};
  __bf16* dsts[5]      = {b_in, b_xp, b_dtp, b_out, b_w3};
  int counts[5] = {4096*1024, 96*2048, 2048*64, 1024*2048, 1024*4096};
  int acc = 0;
  for (int i = 0; i < 5; i++) { ca.src[i] = srcs[i]; ca.dst[i] = dsts[i]; ca.nblk[i] = acc; acc += counts[i] / 2048; }
  ca.nblk[5] = acc;
  cvt_bf16_kernel<<<acc, 256, 0, stream>>>(ca);
  cvt_w12_kernel<<<4096, 256, 0, stream>>>(w1, w2, b_w12);

  dim3 blk(256);
  // 1. xn = rmsnorm(x, norm1_w)
  rmsnorm_kernel<<<TOKS, 256, 0, stream>>>(x, n1w, xn);
  // 2. xz = xn @ in_proj_w.T          (4096x4096, K=1024) -> bf16
  gemm2<128,0,1,0><<<dim3(32,32,1), blk, 0, stream>>>(xn, b_in, xz, nullptr, 2*DI, DM, DM, DM, 2*DI);
  // 3. u_act = silu(causal_conv(u))   -> bf16
  conv_silu_kernel<<<(TOKS*DI)/256, 256, 0, stream>>>(xz, conv_w, conv_b, uact);
  // 4. proj += u_act @ x_proj_w.T     (4096x128pad, K=2048, split-K x8, atomic)
  gemm2<128,0,5,0><<<dim3(1,32,8), blk, 0, stream>>>(uact, b_xp, proj, nullptr, PROJ_LD, DI, DI, DI, PROJ_LD);
  // 5. dt = softplus(dt_r @ dt_proj_w.T + b)   (4096x2048, K=64) -> f32
  gemm2<128,1,2,0><<<dim3(16,32,1), blk, 0, stream>>>(proj, b_dtp, dt, dt_projb, DI, DTR, PROJ_LD, DTR, DI);
  // 6. selective scan (chunked 2-pass) -> y (bf16)
  scan_pass1<<<dim3(DI/64, NC, 2), 64, 0, stream>>>(dt, uact, proj, A_log, aprod, hend);
  scan_pass2<<<64, 256, 0, stream>>>(aprod, hend, hstart);
  scan_pass3<<<dim3(DI/64, NC, 2), 64, 0, stream>>>(dt, uact, proj, xz, A_log, Dp, hstart, yb);
  // 7. h = y @ out_proj_w.T + x       (4096x1024, K=2048) -> f32, BM=64, SWAP
  gemm2<64,0,3,1><<<dim3(64,8,1), blk, 0, stream>>>(yb, b_out, h, x, DM, DI, DI, DI, DM);
  // 8. xn = rmsnorm(h, norm2_w)
  rmsnorm_kernel<<<TOKS, 256, 0, stream>>>(h, n2w, xn);
  // 9+10 fused: hid = silu(xn@w1.T) * (xn@w2.T)  (packed N=8192) -> bf16
  gemm2<128,0,6,0><<<dim3(64,32,1), blk, 0, stream>>>(xn, b_w12, hid, nullptr, 2*DFF, DM, DM, DM, DFF);
  // 11. out = hid @ w3.T + h          (4096x1024, K=4096) -> f32, BM=64, SWAP
  gemm2<64,0,3,1><<<dim3(64,8,1), blk, 0, stream>>>(hid, b_w3, out, h, DM, DFF, DFF, DFF, DM);

  (void)in_sizes; (void)n_in; (void)out_size; (void)ws_size;
}

// Round 7
// 574.500 us; speedup vs baseline: 1.2680x; 1.0441x over previous
//
#include <hip/hip_runtime.h>
#include <hip/hip_bf16.h>

// Shapes (fixed): B=2, L=2048 -> TOK=4096 tokens
#define TOKS 4096
#define DM   1024
#define DI   2048
#define DST  16
#define DTR  64
#define DFF  4096
#define PROJ_LD 128   // x_proj output padded 96 -> 128

// scan chunking
#define NC    32
#define CHUNK 64

typedef __bf16 bf16x8 __attribute__((ext_vector_type(8)));
typedef float  f32x4  __attribute__((ext_vector_type(4)));

__device__ __forceinline__ __bf16 f2bf(float f) {
  union { float f; unsigned u; } v; v.f = f;
  unsigned r = v.u + 0x7fffu + ((v.u >> 16) & 1u);
  union { unsigned short s; __bf16 b; } o; o.s = (unsigned short)(r >> 16);
  return o.b;
}
__device__ __forceinline__ float siluf(float x) { return x / (1.f + __expf(-x)); }
__device__ __forceinline__ float softplusf(float x) { return x > 20.f ? x : log1pf(__expf(x)); }

// async global->LDS, 16B per lane; LDS dest is wave-uniform base + lane*16
__device__ __forceinline__ void gl2lds16(const void* g, void* l) {
  __builtin_amdgcn_global_load_lds((const __attribute__((address_space(1))) void*)g,
                                   (__attribute__((address_space(3))) void*)l, 16, 0, 0);
}

// ---------------------------------------------------------------------------
// Fused f32 -> bf16 conversion, 5 flat weight tensors.
// ---------------------------------------------------------------------------
struct CvtArgs {
  const float* src[5];
  __bf16*      dst[5];
  int nblk[6];
};

__global__ __launch_bounds__(256) void cvt_bf16_kernel(CvtArgs a) {
  int blk = blockIdx.x;
  int seg = 0;
#pragma unroll
  for (int s = 1; s < 5; s++) if (blk >= a.nblk[s]) seg = s;
  size_t base = (size_t)(blk - a.nblk[seg]) * 2048 + threadIdx.x * 8;
  const float* src = a.src[seg] + base;
  __bf16*      dst = a.dst[seg] + base;
  float4 v0 = *(const float4*)src;
  float4 v1 = *(const float4*)(src + 4);
  union { __bf16 b[8]; uint4 u; } t;
  t.b[0]=f2bf(v0.x); t.b[1]=f2bf(v0.y); t.b[2]=f2bf(v0.z); t.b[3]=f2bf(v0.w);
  t.b[4]=f2bf(v1.x); t.b[5]=f2bf(v1.y); t.b[6]=f2bf(v1.z); t.b[7]=f2bf(v1.w);
  *(uint4*)dst = t.u;
}

// w1,w2 -> packed b_w12: 16-row interleave. dst row (r>>4)*32 + (r&15) + 16*isw2.
__global__ __launch_bounds__(256) void cvt_w12_kernel(const float* __restrict__ w1,
                                                      const float* __restrict__ w2,
                                                      __bf16* __restrict__ dst) {
  int blk = blockIdx.x;              // 0..4095
  int isw2 = blk >> 11;
  int b = blk & 2047;                // 2 rows per block
  int r = b * 2 + (threadIdx.x >> 7);
  int col = (threadIdx.x & 127) * 8;
  const float* src = (isw2 ? w2 : w1) + (size_t)r * DM + col;
  int dr = (r >> 4) * 32 + (r & 15) + isw2 * 16;
  float4 v0 = *(const float4*)src;
  float4 v1 = *(const float4*)(src + 4);
  union { __bf16 b[8]; uint4 u; } t;
  t.b[0]=f2bf(v0.x); t.b[1]=f2bf(v0.y); t.b[2]=f2bf(v0.z); t.b[3]=f2bf(v0.w);
  t.b[4]=f2bf(v1.x); t.b[5]=f2bf(v1.y); t.b[6]=f2bf(v1.z); t.b[7]=f2bf(v1.w);
  *(uint4*)&dst[(size_t)dr * DM + col] = t.u;
}

// ---------------------------------------------------------------------------
// RMSNorm: one block per row of 1024 f32, output bf16.
// ---------------------------------------------------------------------------
__global__ __launch_bounds__(256) void rmsnorm_kernel(const float* __restrict__ x,
                                                      const float* __restrict__ w,
                                                      __bf16* __restrict__ out) {
  int row = blockIdx.x;
  const float* xr = x + (size_t)row * DM;
  float4 v = ((const float4*)xr)[threadIdx.x];
  float ss = v.x*v.x + v.y*v.y + v.z*v.z + v.w*v.w;
#pragma unroll
  for (int o = 32; o > 0; o >>= 1) ss += __shfl_xor(ss, o);
  __shared__ float sred[4];
  if ((threadIdx.x & 63) == 0) sred[threadIdx.x >> 6] = ss;
  __syncthreads();
  float tot = sred[0] + sred[1] + sred[2] + sred[3];
  float scale = rsqrtf(tot * (1.f / DM) + 1e-5f);
  float4 wv = ((const float4*)w)[threadIdx.x];
  union { __bf16 b[4]; ushort4 u; } o;
  o.b[0] = f2bf(v.x * scale * wv.x);
  o.b[1] = f2bf(v.y * scale * wv.y);
  o.b[2] = f2bf(v.z * scale * wv.z);
  o.b[3] = f2bf(v.w * scale * wv.w);
  *(ushort4*)&out[(size_t)row * DM + threadIdx.x * 4] = o.u;
}

// ---------------------------------------------------------------------------
// GEMM: C[M,N] = A[M,K] @ B[N,K]^T, BN=128, BK=32, 4 waves, single-buffered.
// ALL geometry compile-time (KK, Z, LDA, LDB, LDC) so address math strength-
// reduces to scalar increments (r6 showed VALUBusy 51% from runtime addr calc).
// SWAP=1: blockIdx.x indexes M so A-sharing blocks land on the same XCD.
// EPI: 1 bf16, 2 softplus(acc+bias[col]) -> bf16, 3 acc+aux f32,
//      6 packed-SwiGLU silu(acc[j-1])*acc[j] bf16,
//      7 split-K partial f32 store at slice blockIdx.z
// ---------------------------------------------------------------------------
template<int BM, int A_F32, int EPI, int SWAP, int KK, int Z, int LDA, int LDB, int LDC>
__global__ __launch_bounds__(256) void gemm2(
    const void* __restrict__ Ap, const __bf16* __restrict__ Bp,
    void* __restrict__ Cp, const void* __restrict__ auxp)
{
  constexpr int FM = BM / 32;          // frag rows per wave
  constexpr int AI = BM / 64;          // A staging instrs per wave
  constexpr int kPer = KK / Z;
  __shared__ __bf16 sA[BM * 32];
  __shared__ __bf16 sB[128 * 32];
  const int tid  = threadIdx.x;
  const int wave = tid >> 6, lane = tid & 63;
  const int bm = SWAP ? blockIdx.x : blockIdx.y;
  const int bn = SWAP ? blockIdx.y : blockIdx.x;
  const int m0 = bm * BM, n0 = bn * 128;
  const int wr = wave >> 1, wc = wave & 1;
  const int frow = lane & 15, fq = lane >> 4;

  f32x4 acc[FM][4] = {};

  const int kBeg = (Z > 1) ? blockIdx.z * kPer : 0;
  const int kEnd = kBeg + kPer;

  const int lrow = lane >> 2;          // 4 lanes per 64B row segment
  const int lcol = (lane & 3) * 8;

  for (int kt = kBeg; kt < kEnd; kt += 32) {
    if (A_F32) {
      int srow = tid >> 1, sh = (tid & 1) * 16;
      const float* src = (const float*)Ap + (size_t)(m0 + srow) * LDA + kt + sh;
      union { __bf16 b[16]; uint4 u[2]; } t;
#pragma unroll
      for (int q = 0; q < 4; q++) {
        float4 v = *(const float4*)(src + q * 4);
        t.b[q*4+0]=f2bf(v.x); t.b[q*4+1]=f2bf(v.y); t.b[q*4+2]=f2bf(v.z); t.b[q*4+3]=f2bf(v.w);
      }
      *(uint4*)&sA[srow * 32 + sh]     = t.u[0];
      *(uint4*)&sA[srow * 32 + sh + 8] = t.u[1];
    } else {
#pragma unroll
      for (int q = 0; q < AI; q++) {
        int idx = wave * AI + q;
        gl2lds16((const __bf16*)Ap + (size_t)(m0 + idx * 16 + lrow) * LDA + kt + lcol,
                 &sA[idx * 512]);
      }
    }
#pragma unroll
    for (int q = 0; q < 2; q++) {
      int idx = wave * 2 + q;
      gl2lds16(Bp + (size_t)(n0 + idx * 16 + lrow) * LDB + kt + lcol, &sB[idx * 512]);
    }
    __syncthreads();

    bf16x8 afr[FM], bfr[4];
#pragma unroll
    for (int i = 0; i < FM; i++)
      afr[i] = *(const bf16x8*)&sA[(wr * (BM/2) + i * 16 + frow) * 32 + fq * 8];
#pragma unroll
    for (int j = 0; j < 4; j++)
      bfr[j] = *(const bf16x8*)&sB[(wc * 64 + j * 16 + frow) * 32 + fq * 8];
#pragma unroll
    for (int i = 0; i < FM; i++)
#pragma unroll
      for (int j = 0; j < 4; j++)
        acc[i][j] = __builtin_amdgcn_mfma_f32_16x16x32_bf16(afr[i], bfr[j], acc[i][j], 0, 0, 0);
    __syncthreads();
  }

  const float*  auxf = (const float*)auxp;
#pragma unroll
  for (int i = 0; i < FM; i++) {
    int gr = m0 + wr * (BM/2) + i * 16 + fq * 4;
#pragma unroll
    for (int j = 0; j < 4; j++) {
      int gc = n0 + wc * 64 + j * 16 + frow;
#pragma unroll
      for (int r = 0; r < 4; r++) {
        float v = acc[i][j][r];
        if (EPI == 6) {
          if (j & 1) {
            int col = (n0 >> 1) + 32 * wc + 16 * (j >> 1) + frow;
            size_t off = (size_t)(gr + r) * LDC + col;
            float g = acc[i][j-1][r];
            ((__bf16*)Cp)[off] = f2bf(siluf(g) * v);
          }
        } else {
          size_t off = (size_t)(gr + r) * LDC + gc;
          if (EPI == 1) ((__bf16*)Cp)[off] = f2bf(v);
          else if (EPI == 2) ((__bf16*)Cp)[off] = f2bf(softplusf(v + auxf[gc]));
          else if (EPI == 3) ((float*)Cp)[off] = v + auxf[off];
          else if (EPI == 7)
            ((float*)Cp)[(size_t)blockIdx.z * (TOKS * PROJ_LD) + off] = v;
        }
      }
    }
  }
}

// sum 8 split-K partial slices -> proj
__global__ __launch_bounds__(256) void xp_reduce_kernel(const float* __restrict__ part,
                                                        float* __restrict__ proj) {
  int i = blockIdx.x * 256 + threadIdx.x;        // float4 index, 131072 total
  float4 s = ((const float4*)part)[i];
#pragma unroll
  for (int z = 1; z < 8; z++) {
    float4 v = ((const float4*)(part + (size_t)z * TOKS * PROJ_LD))[i];
    s.x += v.x; s.y += v.y; s.z += v.z; s.w += v.w;
  }
  ((float4*)proj)[i] = s;
}

// ---------------------------------------------------------------------------
// Causal depthwise conv (width 4) + SiLU.
// ---------------------------------------------------------------------------
__global__ __launch_bounds__(256) void conv_silu_kernel(const __bf16* __restrict__ xz,
                                                        const float* __restrict__ cw,
                                                        const float* __restrict__ cb,
                                                        __bf16* __restrict__ uact) {
  int idx = blockIdx.x * 256 + threadIdx.x;
  int d   = idx & (DI - 1);
  int tok = idx >> 11;
  int l   = tok & 2047;
  float4 wv = *(const float4*)(cw + d * 4);
  const __bf16* up = xz + (size_t)tok * (2 * DI) + d;
  float acc = cb[d];
  if (l >= 3) acc += wv.x * (float)up[-3 * (2 * DI)];
  if (l >= 2) acc += wv.y * (float)up[-2 * (2 * DI)];
  if (l >= 1) acc += wv.z * (float)up[-1 * (2 * DI)];
  acc += wv.w * (float)up[0];
  uact[idx] = f2bf(siluf(acc));
}

// ---------------------------------------------------------------------------
// Selective scan, chunked 2-pass linear recurrence. dt is bf16 now.
// ---------------------------------------------------------------------------
__global__ __launch_bounds__(64) void scan_pass1(const __bf16* __restrict__ dt,
                                                 const __bf16* __restrict__ uact,
                                                 const float* __restrict__ proj,
                                                 const float* __restrict__ A_log,
                                                 float* __restrict__ aprod,
                                                 float* __restrict__ hend) {
  int lane = threadIdx.x;
  int d = blockIdx.x * 64 + lane;
  int c = blockIdx.y, b = blockIdx.z;
  float An[16], h[16], ap[16];
  {
    const float4* a4 = (const float4*)(A_log + (size_t)d * 16);
#pragma unroll
    for (int q = 0; q < 4; q++) {
      float4 v = a4[q];
      An[q*4+0] = -__expf(v.x); An[q*4+1] = -__expf(v.y);
      An[q*4+2] = -__expf(v.z); An[q*4+3] = -__expf(v.w);
    }
  }
#pragma unroll
  for (int n = 0; n < 16; n++) { h[n] = 0.f; ap[n] = 1.f; }

  size_t tok = (size_t)b * 2048 + (size_t)c * CHUNK;
  const __bf16* dtp = dt   + tok * DI + d;
  const __bf16* up  = uact + tok * DI + d;
  const float*  pp  = proj + tok * PROJ_LD;

  for (int t = 0; t < CHUNK; t++) {
    float dtv = (float)*dtp;
    float uv  = (float)*up;
    const float4* b4 = (const float4*)(pp + 64);
    float Bv[16];
#pragma unroll
    for (int q = 0; q < 4; q++) {
      float4 v = b4[q];
      Bv[q*4+0]=v.x; Bv[q*4+1]=v.y; Bv[q*4+2]=v.z; Bv[q*4+3]=v.w;
    }
    float du = dtv * uv;
#pragma unroll
    for (int n = 0; n < 16; n++) {
      float dA = __expf(dtv * An[n]);
      ap[n] *= dA;
      h[n] = fmaf(dA, h[n], du * Bv[n]);
    }
    dtp += DI; up += DI; pp += PROJ_LD;
  }

  size_t off = ((size_t)(b * NC + c) * DI + d) * 16;
#pragma unroll
  for (int q = 0; q < 4; q++) {
    *(float4*)(hend  + off + q*4) = make_float4(h[q*4+0],  h[q*4+1],  h[q*4+2],  h[q*4+3]);
    *(float4*)(aprod + off + q*4) = make_float4(ap[q*4+0], ap[q*4+1], ap[q*4+2], ap[q*4+3]);
  }
}

__global__ __launch_bounds__(256) void scan_pass2(const float* __restrict__ aprod,
                                                  const float* __restrict__ hend,
                                                  float* __restrict__ hstart) {
  int idx = blockIdx.x * 256 + threadIdx.x;
  int b  = idx >> 13;
  int r4 = idx & 8191;
  float4 H = make_float4(0.f, 0.f, 0.f, 0.f);
  for (int c = 0; c < NC; c++) {
    size_t off = (size_t)(b * NC + c) * (DI * 16 / 4) + r4;
    ((float4*)hstart)[off] = H;
    float4 a = ((const float4*)aprod)[off];
    float4 e = ((const float4*)hend)[off];
    H.x = fmaf(a.x, H.x, e.x);
    H.y = fmaf(a.y, H.y, e.y);
    H.z = fmaf(a.z, H.z, e.z);
    H.w = fmaf(a.w, H.w, e.w);
  }
}

__global__ __launch_bounds__(64) void scan_pass3(const __bf16* __restrict__ dt,
                                                 const __bf16* __restrict__ uact,
                                                 const float* __restrict__ proj,
                                                 const __bf16* __restrict__ xz,
                                                 const float* __restrict__ A_log,
                                                 const float* __restrict__ Dp,
                                                 const float* __restrict__ hstart,
                                                 __bf16* __restrict__ y) {
  int lane = threadIdx.x;
  int d = blockIdx.x * 64 + lane;
  int c = blockIdx.y, b = blockIdx.z;
  float An[16], h[16];
  {
    const float4* a4 = (const float4*)(A_log + (size_t)d * 16);
#pragma unroll
    for (int q = 0; q < 4; q++) {
      float4 v = a4[q];
      An[q*4+0] = -__expf(v.x); An[q*4+1] = -__expf(v.y);
      An[q*4+2] = -__expf(v.z); An[q*4+3] = -__expf(v.w);
    }
  }
  {
    size_t off = ((size_t)(b * NC + c) * DI + d) * 16;
#pragma unroll
    for (int q = 0; q < 4; q++) {
      float4 v = *(const float4*)(hstart + off + q*4);
      h[q*4+0]=v.x; h[q*4+1]=v.y; h[q*4+2]=v.z; h[q*4+3]=v.w;
    }
  }
  float Dd = Dp[d];

  size_t tok = (size_t)b * 2048 + (size_t)c * CHUNK;
  const __bf16* dtp = dt   + tok * DI + d;
  const __bf16* up  = uact + tok * DI + d;
  const float*  pp  = proj + tok * PROJ_LD;
  const __bf16* zp  = xz   + tok * (2 * DI) + DI + d;
  __bf16*       yp  = y    + tok * DI + d;

  for (int t = 0; t < CHUNK; t++) {
    float dtv = (float)*dtp;
    float uv  = (float)*up;
    float zv  = (float)*zp;
    const float4* b4 = (const float4*)(pp + 64);
    float Bv[16], Cv[16];
#pragma unroll
    for (int q = 0; q < 4; q++) {
      float4 v = b4[q];
      Bv[q*4+0]=v.x; Bv[q*4+1]=v.y; Bv[q*4+2]=v.z; Bv[q*4+3]=v.w;
      float4 w = b4[q + 4];
      Cv[q*4+0]=w.x; Cv[q*4+1]=w.y; Cv[q*4+2]=w.z; Cv[q*4+3]=w.w;
    }
    float du = dtv * uv;
    float p = 0.f;
#pragma unroll
    for (int n = 0; n < 16; n++) {
      float dA = __expf(dtv * An[n]);
      h[n] = fmaf(dA, h[n], du * Bv[n]);
      p = fmaf(h[n], Cv[n], p);
    }
    *yp = f2bf((p + Dd * uv) * siluf(zv));
    dtp += DI; up += DI; pp += PROJ_LD; zp += 2 * DI; yp += DI;
  }
}

// ---------------------------------------------------------------------------
extern "C" void kernel_launch(void* const* d_in, const int* in_sizes, int n_in,
                              void* d_out, int out_size, void* d_ws, size_t ws_size,
                              hipStream_t stream) {
  const float* x        = (const float*)d_in[0];
  const float* n1w      = (const float*)d_in[1];
  const float* n2w      = (const float*)d_in[2];
  const float* in_projw = (const float*)d_in[3];
  const float* conv_w   = (const float*)d_in[4];
  const float* conv_b   = (const float*)d_in[5];
  const float* x_projw  = (const float*)d_in[6];
  const float* dt_projw = (const float*)d_in[7];
  const float* dt_projb = (const float*)d_in[8];
  const float* A_log    = (const float*)d_in[9];
  const float* Dp       = (const float*)d_in[10];
  const float* out_projw= (const float*)d_in[11];
  const float* w1       = (const float*)d_in[12];
  const float* w2       = (const float*)d_in[13];
  const float* w3       = (const float*)d_in[14];
  float* out = (float*)d_out;

  char* ws = (char*)d_ws;
  __bf16* xz   = (__bf16*)(ws + 0);            // 4096x4096 bf16 = 33554432
  __bf16* uact = (__bf16*)(ws + 33554432);     // 4096x2048 bf16 = 16777216
  float*  proj = (float*) (ws + 50331648);     // 4096x128 f32  =  2097152
  __bf16* dt   = (__bf16*)(ws + 52428800);     // 4096x2048 bf16= 16777216
  __bf16* yb   = (__bf16*)(ws + 85983232);     // 4096x2048 bf16= 16777216
  float*  xpp  = (float*) (ws + 85983232);     // split-K partials 8x2MB (dead before yb written)
  float*  h    = (float*) (ws + 102760448);    // 4096x1024 f32 = 16777216
  __bf16* xn   = (__bf16*)(ws + 119537664);    // 4096x1024 bf16=  8388608
  __bf16* hid  = xz;                           // union: xz dead after scan_pass3
  float* aprod  = (float*)(ws + 102760448);    // overlaps h (h written at step 7)
  float* hend   = (float*)(ws + 111149056);
  float* hstart = (float*)(ws + 119537664);    // overlaps xn
  char* wb = ws + 127926272;
  __bf16* b_in  = (__bf16*)(wb);               // 8388608
  __bf16* b_xp  = (__bf16*)(wb + 8388608);     // 128x2048 (padded) = 524288
  __bf16* b_dtp = (__bf16*)(wb + 8912896);     // 262144
  __bf16* b_out = (__bf16*)(wb + 9175040);     // 4194304
  __bf16* b_w12 = (__bf16*)(wb + 13369344);    // 8192x1024 packed = 16777216
  __bf16* b_w3  = (__bf16*)(wb + 30146560);    // 8388608, end 38535168

  hipMemsetAsync(b_xp, 0, 128 * 2048 * sizeof(__bf16), stream);

  CvtArgs ca;
  const float* srcs[5] = {in_projw, x_projw, dt_projw, out_projw, w3};
  __bf16* dsts[5]      = {b_in, b_xp, b_dtp, b_out, b_w3};
  int counts[5] = {4096*1024, 96*2048, 2048*64, 1024*2048, 1024*4096};
  int acc = 0;
  for (int i = 0; i < 5; i++) { ca.src[i] = srcs[i]; ca.dst[i] = dsts[i]; ca.nblk[i] = acc; acc += counts[i] / 2048; }
  ca.nblk[5] = acc;
  cvt_bf16_kernel<<<acc, 256, 0, stream>>>(ca);
  cvt_w12_kernel<<<4096, 256, 0, stream>>>(w1, w2, b_w12);

  dim3 blk(256);
  // 1. xn = rmsnorm(x, norm1_w)
  rmsnorm_kernel<<<TOKS, 256, 0, stream>>>(x, n1w, xn);
  // 2. xz = xn @ in_proj_w.T          (4096x4096, K=1024) -> bf16
  gemm2<128,0,1,0, 1024,1, DM,DM,4096><<<dim3(32,32,1), blk, 0, stream>>>(xn, b_in, xz, nullptr);
  // 3. u_act = silu(causal_conv(u))   -> bf16
  conv_silu_kernel<<<(TOKS*DI)/256, 256, 0, stream>>>(xz, conv_w, conv_b, uact);
  // 4. x_proj split-K x8 -> partial slices, then reduce -> proj
  gemm2<128,0,7,0, 2048,8, DI,DI,PROJ_LD><<<dim3(1,32,8), blk, 0, stream>>>(uact, b_xp, xpp, nullptr);
  xp_reduce_kernel<<<512, 256, 0, stream>>>(xpp, proj);
  // 5. dt = softplus(dt_r @ dt_proj_w.T + b)   (4096x2048, K=64) -> bf16
  gemm2<128,1,2,0, 64,1, PROJ_LD,DTR,DI><<<dim3(16,32,1), blk, 0, stream>>>(proj, b_dtp, dt, dt_projb);
  // 6. selective scan (chunked 2-pass) -> y (bf16)
  scan_pass1<<<dim3(DI/64, NC, 2), 64, 0, stream>>>(dt, uact, proj, A_log, aprod, hend);
  scan_pass2<<<64, 256, 0, stream>>>(aprod, hend, hstart);
  scan_pass3<<<dim3(DI/64, NC, 2), 64, 0, stream>>>(dt, uact, proj, xz, A_log, Dp, hstart, yb);
  // 7. h = y @ out_proj_w.T + x       (4096x1024, K=2048) -> f32, BM=128 SWAP
  gemm2<128,0,3,1, 2048,1, DI,DI,DM><<<dim3(32,8,1), blk, 0, stream>>>(yb, b_out, h, x);
  // 8. xn = rmsnorm(h, norm2_w)
  rmsnorm_kernel<<<TOKS, 256, 0, stream>>>(h, n2w, xn);
  // 9+10 fused: hid = silu(xn@w1.T) * (xn@w2.T)  (packed N=8192) -> bf16 (overlays xz)
  gemm2<128,0,6,0, 1024,1, DM,DM,DFF><<<dim3(64,32,1), blk, 0, stream>>>(xn, b_w12, hid, nullptr);
  // 11. out = hid @ w3.T + h          (4096x1024, K=4096) -> f32, BM=128 SWAP
  gemm2<128,0,3,1, 4096,1, DFF,DFF,DM><<<dim3(32,8,1), blk, 0, stream>>>(hid, b_w3, out, h);

  (void)in_sizes; (void)n_in; (void)out_size; (void)ws_size;
}